// Round 9
// baseline (99.770 us; speedup 1.0000x reference)
//
#include <hip/hip_runtime.h>
#include <hip/hip_bf16.h>

// NT-Xent (SimCLR) fused loss, MI355X gfx950. Round 9: ZERO-LDS register
// GEMM. R8's persistent decomposition (512 blocks = 2/CU, block = 128-row
// band x 4-5 column tiles, 4 waves in 2x2) but no LDS and no barriers at
// all: A-fragments live in VGPRs (loaded once per block straight from
// global), B-fragments direct-load from global per tile (32 contiguous
// bytes/lane; wm-pair waves share addresses -> L1 broadcast; zn8 = 2 MiB
// fits per-XCD L2). Per tile: issue B loads -> epilogue(prev tile) hides
// the load latency -> MFMA (h=0 with C=0, no acc zero-init).
// FP8 e4m3 + mfma_scale_f32_16x16x128_f8f6f4 (scale=1.0).
//
// ws layout: [S: N floats][pos: N floats][zn8: N*D fp8 bytes]

#define N_TOT 8192
#define BATCH 4096
#define DIM   256                    // fp8 bytes per row
#define NT_TILES 64                  // 8192 / 128

typedef int   v8i32 __attribute__((ext_vector_type(8)));
typedef float f32x4 __attribute__((ext_vector_type(4)));

// One wave per row: 64 lanes x float4 -> 4 fp8 bytes/lane. Also zeros S.
__global__ __launch_bounds__(256) void normalize_kernel(
    const float* __restrict__ z, unsigned char* __restrict__ zn8,
    float* __restrict__ S) {
  const int wave = threadIdx.x >> 6;
  const int lane = threadIdx.x & 63;
  const int row  = blockIdx.x * 4 + wave;
  float4 v = ((const float4*)(z + (size_t)row * DIM))[lane];
  float ss = v.x * v.x + v.y * v.y + v.z * v.z + v.w * v.w;
#pragma unroll
  for (int m = 1; m <= 32; m <<= 1) ss += __shfl_xor(ss, m);
  float inv = 1.0f / sqrtf(ss);
  int p01 = __builtin_amdgcn_cvt_pk_fp8_f32(v.x * inv, v.y * inv, 0, false);
  int p23 = __builtin_amdgcn_cvt_pk_fp8_f32(v.z * inv, v.w * inv, 0, false);
  unsigned int packed =
      ((unsigned int)p01 & 0xffffu) | ((unsigned int)p23 << 16);
  ((unsigned int*)(zn8 + (size_t)row * DIM))[lane] = packed;
  if (threadIdx.x < 4) S[blockIdx.x * 4 + threadIdx.x] = 0.0f;
}

// 32 contiguous bytes -> one K=128 fp8 MFMA operand fragment (8 VGPRs).
__device__ __forceinline__ v8i32 load_frag_g(const unsigned char* p) {
  int4 lo = *(const int4*)p;
  int4 hi = *(const int4*)(p + 16);
  return (v8i32){lo.x, lo.y, lo.z, lo.w, hi.x, hi.y, hi.z, hi.w};
}

// Fused exp/row-sum/col-sum epilogue for one 128x128 tile held in acc.
// C/D layout: row = quad*4 + reg, col = lane&15 per 16x16 fragment.
__device__ __forceinline__ void tile_epilogue(
    const f32x4 acc[4][4], int rb, int cbt, bool isdiag, int wm, int wn,
    int c, int quad, float* __restrict__ S, float* __restrict__ pos) {
  float cs[4] = {0.f, 0.f, 0.f, 0.f};
#pragma unroll
  for (int fm = 0; fm < 4; ++fm) {
#pragma unroll
    for (int r = 0; r < 4; ++r) {
      const int grow = rb * 128 + wm * 64 + fm * 16 + quad * 4 + r;
      float s = 0.f;
#pragma unroll
      for (int fn = 0; fn < 4; ++fn) {
        const int gcol = cbt * 128 + wn * 64 + fn * 16 + c;
        const float logit = acc[fm][fn][r] * 10.0f;
        float e = __expf(logit);
        if (isdiag && gcol == grow) e = 0.f;     // exclude self-similarity
        if ((gcol ^ grow) == BATCH) {            // partner pair i <-> i^B
          pos[grow] = logit;                     // unique writer per element
          pos[gcol] = logit;                     // sim symmetric
        }
        s += e;
        cs[fn] += e;
      }
      s += __shfl_xor(s, 1);
      s += __shfl_xor(s, 2);
      s += __shfl_xor(s, 4);
      s += __shfl_xor(s, 8);
      if (c == 0) atomicAdd(&S[grow], s);
    }
  }
  if (!isdiag) {
    // column sums -> S[col] (transpose contribution of this tile)
#pragma unroll
    for (int fn = 0; fn < 4; ++fn) {
      cs[fn] += __shfl_xor(cs[fn], 16);
      cs[fn] += __shfl_xor(cs[fn], 32);
    }
    if (quad == 0) {
#pragma unroll
      for (int fn = 0; fn < 4; ++fn)
        atomicAdd(&S[cbt * 128 + wn * 64 + fn * 16 + c], cs[fn]);
    }
  }
}

__global__ __launch_bounds__(256, 2) void simclr_tile_kernel(
    const unsigned char* __restrict__ zn8, float* __restrict__ S,
    float* __restrict__ pos) {
  const int g = blockIdx.x;                    // j-group 0..7
  const int rb = blockIdx.y;                   // row band 0..63 (A, fixed)
  const int tid = threadIdx.x;
  const int wave = tid >> 6, lane = tid & 63;
  const int wm = wave >> 1, wn = wave & 1;     // wave quadrant (2x2)
  const int c = lane & 15, quad = lane >> 4;   // MFMA lane coords

  const int ntile = (g == 0 && rb < 32) ? 5 : 4;  // g0 also does j=32

  // A-fragments straight from global into registers, once per block.
  // Lane (c,quad) of fragment (f,h) holds A[row=f*16+c][k=h*128+quad*32..+32].
  v8i32 af[4][2];
#pragma unroll
  for (int f = 0; f < 4; ++f) {
    const unsigned char* arow =
        zn8 + (size_t)(rb * 128 + wm * 64 + f * 16 + c) * DIM + quad * 32;
#pragma unroll
    for (int h = 0; h < 2; ++h) af[f][h] = load_frag_g(arow + h * 128);
  }

  f32x4 acc[4][4];
  int cbPrev = 0;
  bool diagPrev = false, havePrev = false;

  for (int t = 0; t < ntile; ++t) {
    const int jj = (t == 4) ? 32 : (g * 4 + t);
    const int cbt = (rb + jj) & 63;

    // 1. Issue this tile's B-fragment loads (16 dwordx4, fire early).
    v8i32 bf[4][2];
#pragma unroll
    for (int f = 0; f < 4; ++f) {
      const unsigned char* brow =
          zn8 + (size_t)(cbt * 128 + wn * 64 + f * 16 + c) * DIM + quad * 32;
#pragma unroll
      for (int h = 0; h < 2; ++h) bf[f][h] = load_frag_g(brow + h * 128);
    }

    // 2. Previous tile's epilogue runs while those loads are in flight.
    if (havePrev)
      tile_epilogue(acc, rb, cbPrev, diagPrev, wm, wn, c, quad, S, pos);

    // 3. MFMA. h=0 starts from C=0 (no acc zero-init needed).
#pragma unroll
    for (int fm = 0; fm < 4; ++fm)
#pragma unroll
      for (int fn = 0; fn < 4; ++fn)
        acc[fm][fn] = __builtin_amdgcn_mfma_scale_f32_16x16x128_f8f6f4(
            af[fm][0], bf[fn][0], (f32x4){0.f, 0.f, 0.f, 0.f},
            0, 0, 0, 0x7f, 0, 0x7f);
#pragma unroll
    for (int fm = 0; fm < 4; ++fm)
#pragma unroll
      for (int fn = 0; fn < 4; ++fn)
        acc[fm][fn] = __builtin_amdgcn_mfma_scale_f32_16x16x128_f8f6f4(
            af[fm][1], bf[fn][1], acc[fm][fn],
            0, 0, 0, 0x7f, 0, 0x7f);

    cbPrev = cbt;
    diagPrev = (g == 0 && t == 0);
    havePrev = true;
  }
  tile_epilogue(acc, rb, cbPrev, diagPrev, wm, wn, c, quad, S, pos);
}

// loss = mean(log(S_i) - pos_i)
__global__ __launch_bounds__(1024) void finalize_kernel(
    const float* __restrict__ S, const float* __restrict__ pos,
    float* __restrict__ out) {
  const int tid = threadIdx.x;
  float a = 0.f;
  for (int i = tid; i < N_TOT; i += 1024) a += __logf(S[i]) - pos[i];
#pragma unroll
  for (int m = 1; m <= 32; m <<= 1) a += __shfl_xor(a, m);
  __shared__ float red[16];
  if ((tid & 63) == 0) red[tid >> 6] = a;
  __syncthreads();
  if (tid < 16) {
    float v = red[tid];
    v += __shfl_xor(v, 1);
    v += __shfl_xor(v, 2);
    v += __shfl_xor(v, 4);
    v += __shfl_xor(v, 8);
    if (tid == 0) out[0] = v * (1.0f / (float)N_TOT);
  }
}

extern "C" void kernel_launch(void* const* d_in, const int* in_sizes, int n_in,
                              void* d_out, int out_size, void* d_ws,
                              size_t ws_size, hipStream_t stream) {
  const float* z = (const float*)d_in[0];
  float* out = (float*)d_out;
  char* ws = (char*)d_ws;
  float* S = (float*)ws;                                   // N floats
  float* pos = (float*)(ws + N_TOT * sizeof(float));       // N floats
  unsigned char* zn8 =
      (unsigned char*)(ws + 2 * N_TOT * sizeof(float));    // N*D fp8

  normalize_kernel<<<N_TOT / 4, 256, 0, stream>>>(z, zn8, S);
  dim3 grid(8, NT_TILES);
  simclr_tile_kernel<<<grid, 256, 0, stream>>>(zn8, S, pos);
  finalize_kernel<<<1, 1024, 0, stream>>>(S, pos, out);
}

// Round 10
// 90.388 us; speedup vs baseline: 1.1038x; 1.1038x over previous
//
#include <hip/hip_runtime.h>
#include <hip/hip_bf16.h>

// NT-Xent (SimCLR) fused loss, MI355X gfx950. Round 10: shuffle-free rows.
// R9's zero-LDS persistent register GEMM (512 blocks = 2/CU, block = 128-row
// band x 4-5 tiles, fp8 MX MFMA, software-pipelined B loads), but the
// epilogue's 4-deep x16-row __shfl_xor chains (ds_bpermute ~60cyc latency
// each — the invariant ~40us wall across R3..R9) are gone:
//  - row sums accumulate in REGISTERS rs[4][4] across all tiles of the
//    block, flushed once per block via a padded LDS transpose + 1 atomic/row
//  - col sums keep only a 2-deep quad shuffle (8 ops, shallow)
//  - j=32 extra tiles spread across g (g == rb&7) to balance the tail
//
// ws layout: [S: N floats][pos: N floats][zn8: N*D fp8 bytes]

#define N_TOT 8192
#define BATCH 4096
#define DIM   256                    // fp8 bytes per row
#define NT_TILES 64                  // 8192 / 128

typedef int   v8i32 __attribute__((ext_vector_type(8)));
typedef float f32x4 __attribute__((ext_vector_type(4)));

// One wave per row: 64 lanes x float4 -> 4 fp8 bytes/lane. Also zeros S.
__global__ __launch_bounds__(256) void normalize_kernel(
    const float* __restrict__ z, unsigned char* __restrict__ zn8,
    float* __restrict__ S) {
  const int wave = threadIdx.x >> 6;
  const int lane = threadIdx.x & 63;
  const int row  = blockIdx.x * 4 + wave;
  float4 v = ((const float4*)(z + (size_t)row * DIM))[lane];
  float ss = v.x * v.x + v.y * v.y + v.z * v.z + v.w * v.w;
#pragma unroll
  for (int m = 1; m <= 32; m <<= 1) ss += __shfl_xor(ss, m);
  float inv = 1.0f / sqrtf(ss);
  int p01 = __builtin_amdgcn_cvt_pk_fp8_f32(v.x * inv, v.y * inv, 0, false);
  int p23 = __builtin_amdgcn_cvt_pk_fp8_f32(v.z * inv, v.w * inv, 0, false);
  unsigned int packed =
      ((unsigned int)p01 & 0xffffu) | ((unsigned int)p23 << 16);
  ((unsigned int*)(zn8 + (size_t)row * DIM))[lane] = packed;
  if (threadIdx.x < 4) S[blockIdx.x * 4 + threadIdx.x] = 0.0f;
}

// 32 contiguous bytes -> one K=128 fp8 MFMA operand fragment (8 VGPRs).
__device__ __forceinline__ v8i32 load_frag_g(const unsigned char* p) {
  int4 lo = *(const int4*)p;
  int4 hi = *(const int4*)(p + 16);
  return (v8i32){lo.x, lo.y, lo.z, lo.w, hi.x, hi.y, hi.z, hi.w};
}

// Per-tile epilogue: exp, diag mask, partner capture, register row-sum
// accumulation, shallow col reduce + col atomics. NO deep shuffle chains.
__device__ __forceinline__ void tile_epilogue(
    const f32x4 acc[4][4], float rs[4][4], int rb, int cbt, bool isdiag,
    int wm, int wn, int c, int quad, float* __restrict__ S,
    float* __restrict__ pos) {
  float cs[4] = {0.f, 0.f, 0.f, 0.f};
#pragma unroll
  for (int fm = 0; fm < 4; ++fm) {
#pragma unroll
    for (int r = 0; r < 4; ++r) {
      const int grow = rb * 128 + wm * 64 + fm * 16 + quad * 4 + r;
#pragma unroll
      for (int fn = 0; fn < 4; ++fn) {
        const int gcol = cbt * 128 + wn * 64 + fn * 16 + c;
        const float logit = acc[fm][fn][r] * 10.0f;
        float e = __expf(logit);
        if (isdiag && gcol == grow) e = 0.f;     // exclude self-similarity
        if ((gcol ^ grow) == BATCH) {            // partner pair i <-> i^B
          pos[grow] = logit;                     // unique writer per element
          pos[gcol] = logit;                     // sim symmetric
        }
        rs[fm][r] += e;                          // row partial -> registers
        cs[fn] += e;                             // col partial
      }
    }
  }
  if (!isdiag) {
    // col sums: 2-deep shuffle across quads only, then 1 atomic per col.
#pragma unroll
    for (int fn = 0; fn < 4; ++fn) {
      cs[fn] += __shfl_xor(cs[fn], 16);
      cs[fn] += __shfl_xor(cs[fn], 32);
    }
    if (quad == 0) {
#pragma unroll
      for (int fn = 0; fn < 4; ++fn)
        atomicAdd(&S[cbt * 128 + wn * 64 + fn * 16 + c], cs[fn]);
    }
  }
}

__global__ __launch_bounds__(256, 2) void simclr_tile_kernel(
    const unsigned char* __restrict__ zn8, float* __restrict__ S,
    float* __restrict__ pos) {
  const int g = blockIdx.x;                    // j-group 0..7
  const int rb = blockIdx.y;                   // row band 0..63 (A, fixed)
  const int tid = threadIdx.x;
  const int wave = tid >> 6, lane = tid & 63;
  const int wm = wave >> 1, wn = wave & 1;     // wave quadrant (2x2)
  const int c = lane & 15, quad = lane >> 4;   // MFMA lane coords

  // 18.4 KB row-reduction scratch; +36 pad keeps writes 2-way (free) and
  // float4 read phase conflict-free.
  __shared__ float rowbins[128][36];

  const bool extra = (rb < 32) && (g == (rb & 7));   // j=32 tile, spread
  const int ntile = 4 + (extra ? 1 : 0);

  // A-fragments straight from global into registers, once per block.
  v8i32 af[4][2];
#pragma unroll
  for (int f = 0; f < 4; ++f) {
    const unsigned char* arow =
        zn8 + (size_t)(rb * 128 + wm * 64 + f * 16 + c) * DIM + quad * 32;
#pragma unroll
    for (int h = 0; h < 2; ++h) af[f][h] = load_frag_g(arow + h * 128);
  }

  float rs[4][4] = {{0.f, 0.f, 0.f, 0.f}, {0.f, 0.f, 0.f, 0.f},
                    {0.f, 0.f, 0.f, 0.f}, {0.f, 0.f, 0.f, 0.f}};

  f32x4 acc[4][4];
  int cbPrev = 0;
  bool diagPrev = false, havePrev = false;

  for (int t = 0; t < ntile; ++t) {
    const int jj = (t == 4) ? 32 : (g * 4 + t);
    const int cbt = (rb + jj) & 63;

    // 1. Issue this tile's B-fragment loads (fire early).
    v8i32 bf[4][2];
#pragma unroll
    for (int f = 0; f < 4; ++f) {
      const unsigned char* brow =
          zn8 + (size_t)(cbt * 128 + wn * 64 + f * 16 + c) * DIM + quad * 32;
#pragma unroll
      for (int h = 0; h < 2; ++h) bf[f][h] = load_frag_g(brow + h * 128);
    }

    // 2. Previous tile's epilogue runs while those loads are in flight.
    if (havePrev)
      tile_epilogue(acc, rs, rb, cbPrev, diagPrev, wm, wn, c, quad, S, pos);

    // 3. MFMA. h=0 starts from C=0 (no acc zero-init needed).
#pragma unroll
    for (int fm = 0; fm < 4; ++fm)
#pragma unroll
      for (int fn = 0; fn < 4; ++fn)
        acc[fm][fn] = __builtin_amdgcn_mfma_scale_f32_16x16x128_f8f6f4(
            af[fm][0], bf[fn][0], (f32x4){0.f, 0.f, 0.f, 0.f},
            0, 0, 0, 0x7f, 0, 0x7f);
#pragma unroll
    for (int fm = 0; fm < 4; ++fm)
#pragma unroll
      for (int fn = 0; fn < 4; ++fn)
        acc[fm][fn] = __builtin_amdgcn_mfma_scale_f32_16x16x128_f8f6f4(
            af[fm][1], bf[fn][1], acc[fm][fn],
            0, 0, 0, 0x7f, 0, 0x7f);

    cbPrev = cbt;
    diagPrev = (g == 0 && t == 0);
    havePrev = true;
  }
  tile_epilogue(acc, rs, rb, cbPrev, diagPrev, wm, wn, c, quad, S, pos);

  // Block-end row flush: registers -> padded LDS -> 1 atomic per row.
#pragma unroll
  for (int fm = 0; fm < 4; ++fm)
#pragma unroll
    for (int r = 0; r < 4; ++r)
      rowbins[wm * 64 + fm * 16 + quad * 4 + r][wn * 16 + c] = rs[fm][r];
  __syncthreads();
  if (tid < 128) {
    const float4* p = (const float4*)rowbins[tid];   // 144B row stride, 16B-aligned
    float s = 0.f;
#pragma unroll
    for (int k = 0; k < 8; ++k) {
      float4 v = p[k];
      s += v.x + v.y + v.z + v.w;
    }
    atomicAdd(&S[rb * 128 + tid], s);
  }
}

// loss = mean(log(S_i) - pos_i)
__global__ __launch_bounds__(1024) void finalize_kernel(
    const float* __restrict__ S, const float* __restrict__ pos,
    float* __restrict__ out) {
  const int tid = threadIdx.x;
  float a = 0.f;
  for (int i = tid; i < N_TOT; i += 1024) a += __logf(S[i]) - pos[i];
#pragma unroll
  for (int m = 1; m <= 32; m <<= 1) a += __shfl_xor(a, m);
  __shared__ float red[16];
  if ((tid & 63) == 0) red[tid >> 6] = a;
  __syncthreads();
  if (tid < 16) {
    float v = red[tid];
    v += __shfl_xor(v, 1);
    v += __shfl_xor(v, 2);
    v += __shfl_xor(v, 4);
    v += __shfl_xor(v, 8);
    if (tid == 0) out[0] = v * (1.0f / (float)N_TOT);
  }
}

extern "C" void kernel_launch(void* const* d_in, const int* in_sizes, int n_in,
                              void* d_out, int out_size, void* d_ws,
                              size_t ws_size, hipStream_t stream) {
  const float* z = (const float*)d_in[0];
  float* out = (float*)d_out;
  char* ws = (char*)d_ws;
  float* S = (float*)ws;                                   // N floats
  float* pos = (float*)(ws + N_TOT * sizeof(float));       // N floats
  unsigned char* zn8 =
      (unsigned char*)(ws + 2 * N_TOT * sizeof(float));    // N*D fp8

  normalize_kernel<<<N_TOT / 4, 256, 0, stream>>>(z, zn8, S);
  dim3 grid(8, NT_TILES);
  simclr_tile_kernel<<<grid, 256, 0, stream>>>(zn8, S, pos);
  finalize_kernel<<<1, 1024, 0, stream>>>(S, pos, out);
}